// Round 11
// baseline (885.763 us; speedup 1.0000x reference)
//
#include <hip/hip_runtime.h>
#include <math.h>

// Problem constants (from reference)
#define NROWS 18432
#define IN_DIM 1024
#define HID_DIM 4096
#define OUT_DIM 4096
#define NTN 16   // 4096/256 column tiles (both layers)

typedef __attribute__((ext_vector_type(8)))  short bf16x8;
typedef __attribute__((ext_vector_type(16))) float f32x16;

typedef const __attribute__((address_space(1))) char gchar;
typedef __attribute__((address_space(3))) char lchar;

__device__ __forceinline__ unsigned short f2bf(float f) {
    union { float f; unsigned u; } v; v.f = f;
    unsigned r = v.u + 0x7fffu + ((v.u >> 16) & 1u);  // RNE
    return (unsigned short)(r >> 16);
}

__device__ __forceinline__ f32x16 MFMA32(bf16x8 a, bf16x8 b, f32x16 c) {
    return __builtin_amdgcn_mfma_f32_32x32x16_bf16(a, b, c, 0, 0, 0);
}

// ---------------- conversion kernels ----------------

__global__ void cvt_f32_bf16_k(const float4* __restrict__ in, uint4* __restrict__ out, int nvec) {
    int i = blockIdx.x * blockDim.x + threadIdx.x;
    if (i >= nvec) return;
    float4 a = in[2 * i], b = in[2 * i + 1];
    union { unsigned short s[8]; uint4 v; } o;
    o.s[0] = f2bf(a.x); o.s[1] = f2bf(a.y); o.s[2] = f2bf(a.z); o.s[3] = f2bf(a.w);
    o.s[4] = f2bf(b.x); o.s[5] = f2bf(b.y); o.s[6] = f2bf(b.z); o.s[7] = f2bf(b.w);
    out[i] = o.v;
}

// int8 values harness-materialized as int32; exact in bf16
__global__ void cvt_i32_bf16_k(const int4* __restrict__ in, uint4* __restrict__ out, int nvec) {
    int i = blockIdx.x * blockDim.x + threadIdx.x;
    if (i >= nvec) return;
    int4 a = in[2 * i], b = in[2 * i + 1];
    union { unsigned short s[8]; uint4 v; } o;
    o.s[0] = f2bf((float)a.x); o.s[1] = f2bf((float)a.y);
    o.s[2] = f2bf((float)a.z); o.s[3] = f2bf((float)a.w);
    o.s[4] = f2bf((float)b.x); o.s[5] = f2bf((float)b.y);
    o.s[6] = f2bf((float)b.z); o.s[7] = f2bf((float)b.w);
    out[i] = o.v;
}

// ------- m201-template 256x256 8-phase GEMM, 32x32x16 MFMA, BK=64, 2 K-tiles/iter -------
// EXACT round-10 skeleton (stage schedule, vmcnt ledger, barriers, XCD swizzle); only the MFMA
// shape changed 16x16x32 -> 32x32x16 (+20% matrix-pipe rate per m119: 2495 vs 2075 TF; half
// the MFMA and ds_read instruction count, same bytes).
// Fragments: A row frag = 32 rows; lane holds row=lane&31, k=(lane>>5)*8+e (family pattern of
// the VERIFIED 16x16x32 layout); C/D: col=lane&31, row=(reg&3)+8*(reg>>2)+4*(lane>>5) [m74].
// Quadrants (mh,nh): mh = 64-row half (2 frags), nh = 32-col half (1 frag); walk
// (0,0)(0,1)(1,1)(1,0); b0 retained P0->P3, b1 P1->P2. 8 MFMA/phase.
// Swizzle: slot=(s*2+kg)^(row&7) -- every 8-lane group hits 8 distinct 16B slots (0 conflicts);
// stage source pre-inverse-swizzled with (pr_&7) (rule 21, unchanged).
// EPI==0: bf16 gelu(acc*sc+bi); EPI==1: f32 acc*sc+bi. Output row-stride hardcoded 4096.
template<int EPI>
__global__ __launch_bounds__(512, 2)
void gemm32(const unsigned short* __restrict__ A, const unsigned short* __restrict__ B,
            const float* __restrict__ scale, const float* __restrict__ bias,
            void* __restrict__ Cout, int K) {
    extern __shared__ __align__(16) char sm[];   // 131072 bytes dynamic

    const int tid  = threadIdx.x;
    const int lane = tid & 63;
    const int wid  = tid >> 6;
    const int wm   = wid >> 2, wn = wid & 3;

    // T1: bijective XCD swizzle (m204)
    const int nwg  = gridDim.x;
    const int q    = nwg >> 3, r = nwg & 7;
    const int xcd  = blockIdx.x & 7, bidx = blockIdx.x >> 3;
    const int swz  = xcd * q + (xcd < r ? xcd : r) + bidx;
    const int tm   = swz / NTN, tn = swz % NTN;

    const size_t rowbytes = (size_t)K * 2;
    const char* Ag = (const char*)A + (size_t)tm * 256 * rowbytes;
    const char* Bg = (const char*)B + (size_t)tn * 256 * rowbytes;

    const int l32 = lane & 31;
    const int kg  = lane >> 5;   // k-group: k = kg*8 + e

    f32x16 acc[2][2][2] = {};    // [mh][nh][mm]
    bf16x8 aq[2][4], b0[4], b1[4];

    const int NIT = K >> 7;      // iterations (2 K-tiles of 64 each)

// stage one 16KB half: rows HR..HR+127 of the 256-row tile, K-tile TILE, LDS offset LDSOFF.
// LDS dest linear; global source pre-inverse-swizzled (rule 21). UNCHANGED from round 10.
#define STAGE(GB, LDSOFF, HR, TILE) { \
    _Pragma("unroll") for (int ld_ = 0; ld_ < 2; ++ld_) { \
        const int po_ = (ld_ << 13) + (tid << 4); \
        const int pr_ = po_ >> 7; \
        const int pc_ = (po_ & 127) ^ ((pr_ & 7) << 4); \
        __builtin_amdgcn_global_load_lds( \
            (gchar*)((GB) + (size_t)((HR) + pr_) * rowbytes + ((size_t)(TILE) << 7) + (size_t)pc_), \
            (lchar*)(sm + (LDSOFF) + po_), 16, 0, 0); \
    } }

// A frags for 64-row half MH: aq[mm][s], rows MH*64+mm*32+l32, k-step s (8 ds_read_b128)
#define READ_A(BUFOFF, MH) { const char* Ab_ = sm + (BUFOFF) + wm * 16384; \
    _Pragma("unroll") for (int mm_ = 0; mm_ < 2; ++mm_) { \
        const int row_ = (MH) * 64 + mm_ * 32 + l32; \
        const int rb_  = row_ << 7; \
        _Pragma("unroll") for (int s_ = 0; s_ < 4; ++s_) { \
            const int sl_ = ((s_ * 2 + kg) ^ (row_ & 7)) << 4; \
            aq[mm_][s_] = *(const bf16x8*)(Ab_ + rb_ + sl_); } } }

// B frag for 32-col half NH: DST[s], col (wn&1)*64+NH*32+l32 (4 ds_read_b128)
#define READ_B(BUFOFF, NH, DST) { const char* Bb_ = sm + (BUFOFF) + 32768 + (wn >> 1) * 16384; \
    const int col_ = (wn & 1) * 64 + (NH) * 32 + l32; \
    const int cb_  = col_ << 7; \
    _Pragma("unroll") for (int s_ = 0; s_ < 4; ++s_) { \
        const int sl_ = ((s_ * 2 + kg) ^ (col_ & 7)) << 4; \
        DST[s_] = *(const bf16x8*)(Bb_ + cb_ + sl_); } }

// one quadrant x K=64: 2 mm x 4 s = 8 MFMA_32x32
#define MF(MH, NH, BQ) { __builtin_amdgcn_s_setprio(1); \
    _Pragma("unroll") for (int mm_ = 0; mm_ < 2; ++mm_) \
        _Pragma("unroll") for (int s_ = 0; s_ < 4; ++s_) \
            acc[MH][NH][mm_] = MFMA32(aq[mm_][s_], BQ[s_], acc[MH][NH][mm_]); \
    __builtin_amdgcn_s_setprio(0); }

#define SFENCE __builtin_amdgcn_sched_barrier(0)
#define WAITV4 { SFENCE; asm volatile("s_waitcnt vmcnt(4)"); SFENCE; }
#define WAITV0 { SFENCE; asm volatile("s_waitcnt vmcnt(0)"); SFENCE; }
#define BARR   { SFENCE; __builtin_amdgcn_s_barrier(); SFENCE; }

    // prologue: tile0 -> buf0 (4 halves), B(tile1) -> buf1 (2 halves). A(tile1) staged at j=0 P0/P1.
    STAGE(Ag, 0,             0,   0); STAGE(Ag, 16384,         128, 0);
    STAGE(Bg, 32768,         0,   0); STAGE(Bg, 49152,         128, 0);
    STAGE(Bg, 65536 + 32768, 0,   1); STAGE(Bg, 65536 + 49152, 128, 1);
    WAITV4; BARR;   // tile0's 8 loads landed; B(1)'s 4 still fly

    const int NT = K >> 6;
    for (int j = 0; j < NIT; ++j) {
        const int  t0 = 2 * j, t1 = 2 * j + 1;
        const bool p2 = (t0 + 2 < NT);
        const bool p3 = (t1 + 2 < NT);
        const bool lastj = (j == NIT - 1);

        // P0: quadrant (m0,n0) of tile t0 (buf0)
        READ_A(0, 0); READ_B(0, 0, b0);
        STAGE(Ag, 65536, 0, t1);                       // A0(t1) -> buf1
        BARR; MF(0, 0, b0);
        // P1: (m0,n1)
        READ_B(0, 1, b1);
        STAGE(Ag, 65536 + 16384, 128, t1);             // A1(t1) -> buf1
        BARR; MF(0, 1, b1);
        // P2: (m1,n1)
        READ_A(0, 1);
        if (p2) STAGE(Bg, 32768, 0, t0 + 2);           // B0(t0+2) -> buf0
        BARR; MF(1, 1, b1);
        // P3: (m1,n0) — counted wait #1
        if (p2) STAGE(Bg, 49152, 128, t0 + 2);         // B1(t0+2) -> buf0
        if (lastj) { WAITV0; } else { WAITV4; }        // lands A(t1)+B(t1) for P4..P7
        BARR; MF(1, 0, b0);
        // P4: (m0,n0) of tile t1 (buf1)
        READ_A(65536, 0); READ_B(65536, 0, b0);
        if (p2) STAGE(Ag, 0, 0, t0 + 2);               // A0(t0+2) -> buf0
        BARR; MF(0, 0, b0);
        // P5: (m0,n1)
        READ_B(65536, 1, b1);
        if (p2) STAGE(Ag, 16384, 128, t0 + 2);         // A1(t0+2) -> buf0
        BARR; MF(0, 1, b1);
        // P6: (m1,n1)
        READ_A(65536, 1);
        if (p3) STAGE(Bg, 65536 + 32768, 0, t1 + 2);   // B0(t1+2) -> buf1
        BARR; MF(1, 1, b1);
        // P7: (m1,n0) — counted wait #2
        if (p3) STAGE(Bg, 65536 + 49152, 128, t1 + 2); // B1(t1+2) -> buf1
        if (!lastj) { WAITV4; }                        // lands tile t0+2 for next P0..P3
        BARR; MF(1, 0, b0);
    }
#undef STAGE
#undef READ_A
#undef READ_B
#undef MF
#undef SFENCE
#undef WAITV4
#undef WAITV0
#undef BARR

    // epilogue: 32x32 C/D layout: col=lane&31, row=(reg&3)+8*(reg>>2)+4*(lane>>5)  [m74/m101]
    const int rbase = (lane >> 5) << 2;
    #pragma unroll
    for (int mh = 0; mh < 2; ++mh)
    #pragma unroll
    for (int nh = 0; nh < 2; ++nh) {
        const int col = tn * 256 + wn * 64 + nh * 32 + l32;
        const float sc = scale[col];
        const float bi = bias[col];
        #pragma unroll
        for (int mm = 0; mm < 2; ++mm) {
            const int r0 = tm * 256 + wm * 128 + mh * 64 + mm * 32 + rbase;
            #pragma unroll
            for (int rg = 0; rg < 4; ++rg)
                #pragma unroll
                for (int rr = 0; rr < 4; ++rr) {
                    float v = acc[mh][nh][mm][rg * 4 + rr] * sc + bi;
                    const int row = r0 + rg * 8 + rr;
                    if (EPI == 0) {
                        float g = 0.5f * v * (1.0f + erff(v * 0.70710678118654752f));
                        ((unsigned short*)Cout)[(size_t)row * 4096 + col] = f2bf(g);
                    } else {
                        ((float*)Cout)[(size_t)row * 4096 + col] = v;
                    }
                }
        }
    }
}

extern "C" void kernel_launch(void* const* d_in, const int* in_sizes, int n_in,
                              void* d_out, int out_size, void* d_ws, size_t ws_size,
                              hipStream_t stream) {
    const float* x   = (const float*)d_in[0];
    const int*   w1q = (const int*)d_in[1];
    const float* s1  = (const float*)d_in[2];
    const float* b1  = (const float*)d_in[3];
    const int*   w2q = (const int*)d_in[4];
    const float* s2  = (const float*)d_in[5];
    const float* b2  = (const float*)d_in[6];
    float*       out = (float*)d_out;

    // allow 128 KiB dynamic LDS (idempotent, not a stream op)
    hipFuncSetAttribute((const void*)gemm32<0>, hipFuncAttributeMaxDynamicSharedMemorySize, 131072);
    hipFuncSetAttribute((const void*)gemm32<1>, hipFuncAttributeMaxDynamicSharedMemorySize, 131072);

    char* ws = (char*)d_ws;
    const size_t XBF  = (size_t)NROWS   * IN_DIM  * 2;
    const size_t W1BF = (size_t)HID_DIM * IN_DIM  * 2;
    const size_t W2BF = (size_t)OUT_DIM * HID_DIM * 2;
    const size_t FIXED = XBF + W1BF + W2BF;

    unsigned short* xbf  = (unsigned short*)ws;
    unsigned short* w1bf = (unsigned short*)(ws + XBF);
    unsigned short* w2bf = (unsigned short*)(ws + XBF + W1BF);
    unsigned short* hbuf = (unsigned short*)(ws + FIXED);

    {
        int nvx = NROWS * IN_DIM / 8;
        cvt_f32_bf16_k<<<(nvx + 255) / 256, 256, 0, stream>>>((const float4*)x, (uint4*)xbf, nvx);
        int nv1 = HID_DIM * IN_DIM / 8;
        cvt_i32_bf16_k<<<(nv1 + 255) / 256, 256, 0, stream>>>((const int4*)w1q, (uint4*)w1bf, nv1);
        int nv2 = OUT_DIM * HID_DIM / 8;
        cvt_i32_bf16_k<<<(nv2 + 255) / 256, 256, 0, stream>>>((const int4*)w2q, (uint4*)w2bf, nv2);
    }

    // chunk M (multiples of 256) so h fits in remaining workspace
    size_t avail = (ws_size > FIXED) ? (ws_size - FIXED) : 0;
    long rp = (long)(avail / ((size_t)HID_DIM * 2));
    rp = (rp / 256) * 256;
    if (rp > NROWS) rp = NROWS;
    if (rp < 256)   rp = 256;

    for (int r0 = 0; r0 < NROWS; r0 += (int)rp) {
        int rows = (int)(((long)(NROWS - r0) < rp) ? (NROWS - r0) : rp);
        dim3 g(NTN * (rows / 256));
        gemm32<0><<<g, 512, 131072, stream>>>(xbf + (size_t)r0 * IN_DIM, w1bf, s1, b1,
                                              (void*)hbuf, IN_DIM);
        gemm32<1><<<g, 512, 131072, stream>>>(hbuf, w2bf, s2, b2,
                                              (void*)(out + (size_t)r0 * OUT_DIM), HID_DIM);
    }
    (void)in_sizes; (void)n_in; (void)out_size;
}

// Round 12
// 827.395 us; speedup vs baseline: 1.0705x; 1.0705x over previous
//
#include <hip/hip_runtime.h>
#include <math.h>

// Problem constants (from reference)
#define NROWS 18432
#define IN_DIM 1024
#define HID_DIM 4096
#define OUT_DIM 4096
#define NTN 16   // 4096/256 column tiles (both layers)

typedef __attribute__((ext_vector_type(8))) short bf16x8;
typedef __attribute__((ext_vector_type(4))) float f32x4;

typedef const __attribute__((address_space(1))) char gchar;
typedef __attribute__((address_space(3))) char lchar;

__device__ __forceinline__ unsigned short f2bf(float f) {
    union { float f; unsigned u; } v; v.f = f;
    unsigned r = v.u + 0x7fffu + ((v.u >> 16) & 1u);  // RNE
    return (unsigned short)(r >> 16);
}

__device__ __forceinline__ f32x4 MFMA16(bf16x8 a, bf16x8 b, f32x4 c) {
    return __builtin_amdgcn_mfma_f32_16x16x32_bf16(a, b, c, 0, 0, 0);
}

// ---------------- conversion kernels ----------------

__global__ void cvt_f32_bf16_k(const float4* __restrict__ in, uint4* __restrict__ out, int nvec) {
    int i = blockIdx.x * blockDim.x + threadIdx.x;
    if (i >= nvec) return;
    float4 a = in[2 * i], b = in[2 * i + 1];
    union { unsigned short s[8]; uint4 v; } o;
    o.s[0] = f2bf(a.x); o.s[1] = f2bf(a.y); o.s[2] = f2bf(a.z); o.s[3] = f2bf(a.w);
    o.s[4] = f2bf(b.x); o.s[5] = f2bf(b.y); o.s[6] = f2bf(b.z); o.s[7] = f2bf(b.w);
    out[i] = o.v;
}

// int8 values harness-materialized as int32; exact in bf16
__global__ void cvt_i32_bf16_k(const int4* __restrict__ in, uint4* __restrict__ out, int nvec) {
    int i = blockIdx.x * blockDim.x + threadIdx.x;
    if (i >= nvec) return;
    int4 a = in[2 * i], b = in[2 * i + 1];
    union { unsigned short s[8]; uint4 v; } o;
    o.s[0] = f2bf((float)a.x); o.s[1] = f2bf((float)a.y);
    o.s[2] = f2bf((float)a.z); o.s[3] = f2bf((float)a.w);
    o.s[4] = f2bf((float)b.x); o.s[5] = f2bf((float)b.y);
    o.s[6] = f2bf((float)b.z); o.s[7] = f2bf((float)b.w);
    out[i] = o.v;
}

// -------- 256x256 8-phase GEMM, 16x16x32, REGISTER-PIPELINED phases (read-one-ahead) --------
// Round-10 skeleton (tiles a=2j/b=2j+1, buf0/buf1, quadrant walk (m0n0)(m0n1)(m1n1)(m1n0)),
// but each phase = {[vmcnt]; BARR; stage; setprio1; MFMA(frags read LAST phase); setprio0;
// ds_reads(NEXT phase's frags)}. MFMAs have no dep on this phase's reads -> issue immediately;
// reads complete under the MFMA cluster (within-wave LDS||MFMA overlap; rounds 4-11 all
// consumed same-phase reads -> lgkm-serialized, capped ~49% MfmaUtil).
// Register reuse (A-set shared lo/hi, B0/B1 single sets) is safe: reads placed after the MFMA
// cluster; reg-WAR preserves order. Frag budget identical to round 10 (64 VGPR).
// Stage-after-barrier fixes the 1-phase-skew WAR race (all waves past BARR(p) finished p-1).
// Stages: P0:A0(b),P1:A1(b)->buf1; P2:A0(c),P3:A1(c),P4:B0(c),P5:B1(c)->buf0; P6:B0(d),
// P7:B1(d)->buf1. Reads: P0->B1(a); P1->Ahi(a); P3->Alo(b),B0(b); P4->B1(b); P5->Ahi(b);
// P7->Alo(c),B0(c). Waits: vmcnt(2)@P3 (completes thru A1(b)@P1), vmcnt(2)@P7 (thru B1(c)@P5),
// prologue vmcnt(4); tail drains v0@P3, skips P7 wait+reads. Ledger verified steady-state
// self-consistent; every WAR >= 1 barrier.
// EPI==0: bf16 gelu(acc*sc+bi); EPI==1: f32 acc*sc+bi. Output row-stride hardcoded 4096.
template<int EPI>
__global__ __launch_bounds__(512, 2)
void gemmpl(const unsigned short* __restrict__ A, const unsigned short* __restrict__ B,
            const float* __restrict__ scale, const float* __restrict__ bias,
            void* __restrict__ Cout, int K) {
    extern __shared__ __align__(16) char sm[];   // 131072 bytes dynamic

    const int tid  = threadIdx.x;
    const int lane = tid & 63;
    const int wid  = tid >> 6;
    const int wm   = wid >> 2, wn = wid & 3;

    // T1: bijective XCD swizzle (m204)
    const int nwg  = gridDim.x;
    const int q    = nwg >> 3, r = nwg & 7;
    const int xcd  = blockIdx.x & 7, bidx = blockIdx.x >> 3;
    const int swz  = xcd * q + (xcd < r ? xcd : r) + bidx;
    const int tm   = swz / NTN, tn = swz % NTN;

    const size_t rowbytes = (size_t)K * 2;
    const char* Ag = (const char*)A + (size_t)tm * 256 * rowbytes;
    const char* Bg = (const char*)B + (size_t)tn * 256 * rowbytes;

    const int l16 = lane & 15;
    const int cgi = lane >> 4;
    const int sw  = l16 & 7;
    const int c0  = ((cgi       ^ sw) << 4);   // swizzled byte-slot, k-step 0
    const int c1  = (((4 | cgi) ^ sw) << 4);   // swizzled byte-slot, k-step 1

    f32x4  acc[8][4] = {};
    bf16x8 aq[4][2], b0[2][2], b1[2][2];

    const int NIT = K >> 7;   // iterations (2 K-tiles of 64 each)

#define STAGE(GB, LDSOFF, HR, TILE) { \
    _Pragma("unroll") for (int ld_ = 0; ld_ < 2; ++ld_) { \
        const int po_ = (ld_ << 13) + (tid << 4); \
        const int pr_ = po_ >> 7; \
        const int pc_ = (po_ & 127) ^ ((pr_ & 7) << 4); \
        __builtin_amdgcn_global_load_lds( \
            (gchar*)((GB) + (size_t)((HR) + pr_) * rowbytes + ((size_t)(TILE) << 7) + (size_t)pc_), \
            (lchar*)(sm + (LDSOFF) + po_), 16, 0, 0); \
    } }

#define READ_A(BUFOFF, MH) { const char* Ab_ = sm + (BUFOFF) + wm * 16384; \
    _Pragma("unroll") for (int mm_ = 0; mm_ < 4; ++mm_) { \
        const int ro_ = (((MH) * 64) + mm_ * 16 + l16) << 7; \
        aq[mm_][0] = *(const bf16x8*)(Ab_ + ro_ + c0); \
        aq[mm_][1] = *(const bf16x8*)(Ab_ + ro_ + c1); } }

#define READ_B(BUFOFF, NH, DST) { const char* Bb_ = sm + (BUFOFF) + 32768 + (wn >> 1) * 16384; \
    _Pragma("unroll") for (int nn_ = 0; nn_ < 2; ++nn_) { \
        const int ro_ = (((wn & 1) * 64) + (NH) * 32 + nn_ * 16 + l16) << 7; \
        DST[nn_][0] = *(const bf16x8*)(Bb_ + ro_ + c0); \
        DST[nn_][1] = *(const bf16x8*)(Bb_ + ro_ + c1); } }

#define MF(MH, NH, BQ) { __builtin_amdgcn_s_setprio(1); \
    _Pragma("unroll") for (int mm_ = 0; mm_ < 4; ++mm_) \
        _Pragma("unroll") for (int nn_ = 0; nn_ < 2; ++nn_) { \
            acc[(MH)*4+mm_][(NH)*2+nn_] = MFMA16(aq[mm_][0], BQ[nn_][0], acc[(MH)*4+mm_][(NH)*2+nn_]); \
            acc[(MH)*4+mm_][(NH)*2+nn_] = MFMA16(aq[mm_][1], BQ[nn_][1], acc[(MH)*4+mm_][(NH)*2+nn_]); } \
    __builtin_amdgcn_s_setprio(0); }

#define SFENCE __builtin_amdgcn_sched_barrier(0)
#define WAITV2 { SFENCE; asm volatile("s_waitcnt vmcnt(2)"); SFENCE; }
#define WAITV4 { SFENCE; asm volatile("s_waitcnt vmcnt(4)"); SFENCE; }
#define WAITV0 { SFENCE; asm volatile("s_waitcnt vmcnt(0)"); SFENCE; }
#define BARR   { SFENCE; __builtin_amdgcn_s_barrier(); SFENCE; }

    // prologue: A(0),B(0)->buf0; B(1)->buf1. Leave B(1)'s 4 loads in flight.
    STAGE(Ag, 0,             0,   0); STAGE(Ag, 16384,         128, 0);
    STAGE(Bg, 32768,         0,   0); STAGE(Bg, 49152,         128, 0);
    STAGE(Bg, 65536 + 32768, 0,   1); STAGE(Bg, 65536 + 49152, 128, 1);
    WAITV4; BARR;
    READ_A(0, 0); READ_B(0, 0, b0);   // preread for P0's MFMA (tile 0, quadrant m0n0)

    const int NT = K >> 6;
    for (int j = 0; j < NIT; ++j) {
        const int  tb = 2 * j + 1, tc = 2 * j + 2, td = 2 * j + 3;
        const bool lastj = (j == NIT - 1);

        // P0: MFMA m0n0(a); stage A0(b)->buf1; read B1(a)
        BARR;
        STAGE(Ag, 65536, 0, tb);
        MF(0, 0, b0);
        READ_B(0, 1, b1);
        // P1: MFMA m0n1(a); stage A1(b)->buf1; read A-hi(a)
        BARR;
        STAGE(Ag, 65536 + 16384, 128, tb);
        MF(0, 1, b1);
        READ_A(0, 1);
        // P2: MFMA m1n1(a); stage A0(c)->buf0
        BARR;
        if (!lastj) STAGE(Ag, 0, 0, tc);
        MF(1, 1, b1);
        // P3: wait; MFMA m1n0(a); stage A1(c)->buf0; read A-lo(b),B0(b)
        if (lastj) { WAITV0; } else { WAITV2; }   // completes thru A1(b)@P1
        BARR;
        if (!lastj) STAGE(Ag, 16384, 128, tc);
        MF(1, 0, b0);
        READ_A(65536, 0); READ_B(65536, 0, b0);
        // P4: MFMA m0n0(b); stage B0(c)->buf0; read B1(b)
        BARR;
        if (!lastj) STAGE(Bg, 32768, 0, tc);
        MF(0, 0, b0);
        READ_B(65536, 1, b1);
        // P5: MFMA m0n1(b); stage B1(c)->buf0; read A-hi(b)
        BARR;
        if (!lastj) STAGE(Bg, 49152, 128, tc);
        MF(0, 1, b1);
        READ_A(65536, 1);
        // P6: MFMA m1n1(b); stage B0(d)->buf1
        BARR;
        if (!lastj) STAGE(Bg, 65536 + 32768, 0, td);
        MF(1, 1, b1);
        // P7: wait; MFMA m1n0(b); stage B1(d)->buf1; preread A-lo(c),B0(c)
        if (!lastj) { WAITV2; }                   // completes thru B1(c)@P5
        BARR;
        if (!lastj) STAGE(Bg, 65536 + 49152, 128, td);
        MF(1, 0, b0);
        if (!lastj) { READ_A(0, 0); READ_B(0, 0, b0); }
    }
#undef STAGE
#undef READ_A
#undef READ_B
#undef MF
#undef SFENCE
#undef WAITV2
#undef WAITV4
#undef WAITV0
#undef BARR

    // epilogue: C/D frag layout col=lane&15, row=(lane>>4)*4+r  [m89/m91]
    const int rg = (lane >> 4) << 2;
    #pragma unroll
    for (int nq = 0; nq < 4; ++nq) {
        const int col = tn * 256 + wn * 64 + (nq >> 1) * 32 + (nq & 1) * 16 + l16;
        const float sc = scale[col];
        const float bi = bias[col];
        #pragma unroll
        for (int mq = 0; mq < 8; ++mq) {
            const int row0 = tm * 256 + wm * 128 + (mq >> 2) * 64 + (mq & 3) * 16 + rg;
            #pragma unroll
            for (int rr = 0; rr < 4; ++rr) {
                float v = acc[mq][nq][rr] * sc + bi;
                if (EPI == 0) {
                    float g = 0.5f * v * (1.0f + erff(v * 0.70710678118654752f));
                    ((unsigned short*)Cout)[(size_t)(row0 + rr) * 4096 + col] = f2bf(g);
                } else {
                    ((float*)Cout)[(size_t)(row0 + rr) * 4096 + col] = v;
                }
            }
        }
    }
}

extern "C" void kernel_launch(void* const* d_in, const int* in_sizes, int n_in,
                              void* d_out, int out_size, void* d_ws, size_t ws_size,
                              hipStream_t stream) {
    const float* x   = (const float*)d_in[0];
    const int*   w1q = (const int*)d_in[1];
    const float* s1  = (const float*)d_in[2];
    const float* b1  = (const float*)d_in[3];
    const int*   w2q = (const int*)d_in[4];
    const float* s2  = (const float*)d_in[5];
    const float* b2  = (const float*)d_in[6];
    float*       out = (float*)d_out;

    // allow 128 KiB dynamic LDS (idempotent, not a stream op)
    hipFuncSetAttribute((const void*)gemmpl<0>, hipFuncAttributeMaxDynamicSharedMemorySize, 131072);
    hipFuncSetAttribute((const void*)gemmpl<1>, hipFuncAttributeMaxDynamicSharedMemorySize, 131072);

    char* ws = (char*)d_ws;
    const size_t XBF  = (size_t)NROWS   * IN_DIM  * 2;
    const size_t W1BF = (size_t)HID_DIM * IN_DIM  * 2;
    const size_t W2BF = (size_t)OUT_DIM * HID_DIM * 2;
    const size_t FIXED = XBF + W1BF + W2BF;

    unsigned short* xbf  = (unsigned short*)ws;
    unsigned short* w1bf = (unsigned short*)(ws + XBF);
    unsigned short* w2bf = (unsigned short*)(ws + XBF + W1BF);
    unsigned short* hbuf = (unsigned short*)(ws + FIXED);

    {
        int nvx = NROWS * IN_DIM / 8;
        cvt_f32_bf16_k<<<(nvx + 255) / 256, 256, 0, stream>>>((const float4*)x, (uint4*)xbf, nvx);
        int nv1 = HID_DIM * IN_DIM / 8;
        cvt_i32_bf16_k<<<(nv1 + 255) / 256, 256, 0, stream>>>((const int4*)w1q, (uint4*)w1bf, nv1);
        int nv2 = OUT_DIM * HID_DIM / 8;
        cvt_i32_bf16_k<<<(nv2 + 255) / 256, 256, 0, stream>>>((const int4*)w2q, (uint4*)w2bf, nv2);
    }

    // chunk M (multiples of 256) so h fits in remaining workspace
    size_t avail = (ws_size > FIXED) ? (ws_size - FIXED) : 0;
    long rp = (long)(avail / ((size_t)HID_DIM * 2));
    rp = (rp / 256) * 256;
    if (rp > NROWS) rp = NROWS;
    if (rp < 256)   rp = 256;

    for (int r0 = 0; r0 < NROWS; r0 += (int)rp) {
        int rows = (int)(((long)(NROWS - r0) < rp) ? (NROWS - r0) : rp);
        dim3 g(NTN * (rows / 256));
        gemmpl<0><<<g, 512, 131072, stream>>>(xbf + (size_t)r0 * IN_DIM, w1bf, s1, b1,
                                              (void*)hbuf, IN_DIM);
        gemmpl<1><<<g, 512, 131072, stream>>>(hbuf, w2bf, s2, b2,
                                              (void*)(out + (size_t)r0 * OUT_DIM), HID_DIM);
    }
    (void)in_sizes; (void)n_in; (void)out_size;
}